// Round 8
// baseline (567.349 us; speedup 1.0000x reference)
//
#include <hip/hip_runtime.h>
#include <stdint.h>

#define NPIX 65536      // 256*256
#define NRE  65280      // right edges: 256 rows * 255
#define NE   130560     // total edges
#define NIMG 4
#define LTPB 256                 // local kernel threads (4 waves -> cheap barriers)
#define ETPB 256                 // endgame threads
#define NBLK_L (NIMG*32)         // 128 local blocks (32 tiles/image, 32x64 each)
#define TPIX 2048
#define EPAD 4096                // local edge-id space (H:[0,2048) V:[2048,4096))
#define KMAX 8192                // max components/image for LDS endgame
#define HSZ  1024                // endgame LDS dedupe hash slots
#define LHSZ 2048                // local emit dedupe hash slots
typedef unsigned long long u64;

// union-find, path compression; roots stable within a phase -> races benign
__device__ __forceinline__ int ufind(unsigned* lbl, int x){
  int r = x, c = (int)lbl[r];
  while (c != r){ r = c; c = (int)lbl[r]; }
  while ((int)lbl[x] != r){ int n = (int)lbl[x]; lbl[x] = (unsigned)r; x = n; }
  return r;
}
__device__ __forceinline__ int ufind16(unsigned short* uf, int x){
  int r = x, c = (int)uf[r];
  while (c != r){ r = c; c = (int)uf[r]; }
  while ((int)uf[x] != r){ int n = (int)uf[x]; uf[x] = (unsigned short)r; x = n; }
  return r;
}

// ---------------- local (tile) kernel: LDS union-find contraction ----------------
__global__ __launch_bounds__(LTPB)
void ph0_local(const float* __restrict__ prob, const float* __restrict__ roi,
               float* __restrict__ Fg, float* __restrict__ LIFEg,
               unsigned* __restrict__ LBLg, u64* __restrict__ LAg,
               unsigned* __restrict__ C, unsigned* __restrict__ C2,
               unsigned* __restrict__ MAPg, unsigned* __restrict__ KGg)
{
  const int blk = blockIdx.x;
  const int img = blk >> 5;
  const int tile = blk & 31;
  const int tr = tile >> 2, tc = tile & 3;     // 8 rows x 4 cols of tiles
  const int gr0 = tr*32, gc0 = tc*64;
  const int tid = threadIdx.x;
  const int lane = tid & 63;

  const float* pm = prob + img*NPIX;
  const float* rm = roi  + img*NPIX;
  float* F = Fg + img*NPIX;
  float* LIFE = LIFEg + img*NPIX;
  unsigned* LBL = LBLg + img*NPIX;
  unsigned* MAP = MAPg + img*NPIX;
  unsigned* KG  = KGg  + img*NPIX;
  u64* LA = LAg + (size_t)img*NE;

  __shared__ float          sf[TPIX];      // 8 KB
  __shared__ unsigned       slbl[TPIX];    // 8 KB (later: dedupe hash weights)
  __shared__ unsigned       sme[TPIX];     // 8 KB (min weight per root; later pos-map)
  __shared__ unsigned short el[2][EPAD];   // 16 KB ping-pong edge lists (free half: hash keys)
  __shared__ unsigned       aux[EPAD];     // 16 KB round-start roots (a|b<<16)
  __shared__ unsigned       bkw[192];      // cut-edge blocker weights
  __shared__ unsigned short bkp[192];      // blocker pixel (local id)
  __shared__ int s_n[3];                   // rotating round counters

  for (int p = tid; p < TPIX; p += LTPB){
    int gp = ((gr0 + (p>>6))<<8) + gc0 + (p&63);
    float fv = 1.0f - pm[gp]*rm[gp];
    sf[p] = fv; slbl[p] = (unsigned)p;
    F[gp] = fv; LIFE[gp] = 0.0f;
  }
  if (tid < 3) s_n[tid] = 0;
  // blocker table: for each tile-boundary pixel, min cut-edge weight
  for (int s = tid; s < 192; s += LTPB){
    unsigned wv = 0xFFFFFFFFu; int p = 0; int gq = -1;
    if (s < 32){ if (tc > 0){ p = s*64;        gq = ((gr0+s)<<8)    + gc0 - 1;  } }
    else if (s < 64){ int k=s-32;  if (tc < 3){ p = k*64+63;  gq = ((gr0+k)<<8)  + gc0 + 64; } }
    else if (s < 128){ int k=s-64; if (tr > 0){ p = k;        gq = ((gr0-1)<<8)  + gc0 + k;  } }
    else { int k=s-128;            if (tr < 7){ p = 31*64+k;  gq = ((gr0+32)<<8) + gc0 + k;  } }
    if (gq >= 0){
      int gp = ((gr0 + (p>>6))<<8) + gc0 + (p&63);
      float fp = 1.0f - pm[gp]*rm[gp];
      float fq = 1.0f - pm[gq]*rm[gq];
      wv = __float_as_uint(fmaxf(fp, fq));
    }
    bkw[s] = wv; bkp[s] = (unsigned short)p;
  }
  __syncthreads();

  // ---- local rounds: 3 barriers/round; exit when list stops shrinking ----
  int M = EPAD, cur = 0;
  for (int rd = 0; rd < 100000; ++rd){
    int nxt = cur ^ 1;
    for (int i = tid; i < TPIX; i += LTPB) sme[i] = 0xFFFFFFFFu;
    if (tid == 0) s_n[(rd+1)%3] = 0;
    __syncthreads();                       // A: prev fires + resets visible
    if (tid < 192){
      unsigned wv = bkw[tid];
      if (wv != 0xFFFFFFFFu) atomicMin(&sme[ufind(slbl, (int)bkp[tid])], wv);
    }
    int Mpad = (M + 63) & ~63;
    // phase 1: relabel, compact survivors, per-root min weight
    for (int idx = tid; idx < Mpad; idx += LTPB){
      bool keep = false; int e=0,u=0,v=0,a=0,b=0;
      if (idx < M){
        e = (rd == 0) ? idx : (int)el[cur][idx];
        bool valid;
        if (e < 2048){ u=e; v=e+1; valid = ((e&63)!=63); }
        else { u=e-2048; v=u+64; valid = ((u>>6)!=31); }
        if (valid){
          a = ufind(slbl,u); b = ufind(slbl,v);
          if (a != b){
            unsigned wb = __float_as_uint(fmaxf(sf[u],sf[v]));
            atomicMin(&sme[a],wb); atomicMin(&sme[b],wb);
            keep = true;
          }
        }
      }
      u64 m = __ballot(keep);
      if (m){
        int pos0 = __popcll(m & ((1ULL<<lane)-1));
        int leader = __ffsll((long long)m)-1;
        int base = 0;
        if (lane == leader) base = atomicAdd(&s_n[rd%3], __popcll(m));
        base = __shfl(base, leader);
        if (keep){
          el[nxt][base+pos0] = (unsigned short)e;
          aux[base+pos0] = (unsigned)a | ((unsigned)b<<16);
        }
      }
    }
    __syncthreads();                       // B: mins + list complete
    int n = s_n[rd%3];
    cur = nxt;
    // n == M  <=>  previous round had zero fires  =>  state is stable (blocked)
    if (n == M || n == 0){ M = n; break; }
    M = n;
    // phase 2: fire via round-start roots (frozen in aux) — exact elder rule
    for (int idx = tid; idx < M; idx += LTPB){
      int e = (int)el[cur][idx];
      unsigned ab = aux[idx];
      int a = (int)(ab & 0xFFFFu), b = (int)(ab >> 16);
      int u, v;
      if (e < 2048){ u = e; v = e + 1; } else { u = e - 2048; v = u + 64; }
      float w = fmaxf(sf[u], sf[v]);
      unsigned wb = __float_as_uint(w);
      float fa = sf[a], fb = sf[b];
      bool bd = (fb < fa) || ((fb == fa) && (b < a));   // local order == global order in-tile
      int die = bd ? a : b, keep = bd ? b : a;
      if (sme[die] == wb){
        slbl[die] = (unsigned)keep;
        int gd = ((gr0 + (die>>6))<<8) + gc0 + (die&63);
        LIFE[gd] = w - (bd ? fa : fb);
      }
    }
    __syncthreads();                       // C: fires + sme reads done before next reset
  }

  // ---- final relabel, compact roots to dense per-image ids ----
  for (int p = tid; p < TPIX; p += LTPB){
    int r = ufind(slbl, p);
    int gp = ((gr0 + (p>>6))<<8) + gc0 + (p&63);
    LBL[gp] = (unsigned)(((gr0 + (r>>6))<<8) + gc0 + (r&63));
  }
  __syncthreads();                         // slbl fully compressed; sme reusable
  for (int p = tid; p < TPIX; p += LTPB){
    if ((int)slbl[p] == p){
      unsigned pos = atomicAdd(&C2[img], 1u);
      sme[p] = pos;                        // in-tile pos map
      unsigned gp = (unsigned)(((gr0 + (p>>6))<<8) + gc0 + (p&63));
      MAP[gp] = pos;
      KG[pos] = gp;
    }
  }
  __syncthreads();

  // ---- emit surviving internal edges, deduped per root-pair ----
  unsigned* hk = (unsigned*)&el[cur ^ 1][0];   // 2048 u32 slots (free ping-pong half)
  unsigned* hw = slbl;                          // 2048 u32 slots (dead)
  for (int i = tid; i < LHSZ; i += LTPB){ hk[i] = 0xFFFFFFFFu; hw[i] = 0xFFFFFFFFu; }
  __syncthreads();

  unsigned* ctr = &C[img];
  int Mpad2 = (M + 63) & ~63;
  for (int idx = tid; idx < Mpad2; idx += LTPB){
    bool spill = false;
    u64 rec = 0;
    if (idx < M){
      int e = (int)el[cur][idx];
      unsigned ab = aux[idx];              // round-start roots == final roots (0 fires)
      int a = (int)(ab & 0xFFFFu), b = (int)(ab >> 16);
      int u, v;
      if (e < 2048){ u = e; v = e + 1; } else { u = e - 2048; v = u + 64; }
      unsigned wb = __float_as_uint(fmaxf(sf[u], sf[v]));
      int lo = a < b ? a : b, hi = a < b ? b : a;
      unsigned key = ((unsigned)lo << 11) | (unsigned)hi;   // a,b < 2048 -> 22 bits
      unsigned h = ((key * 2654435761u) >> 21) & (LHSZ-1);
      bool ins = false;
      #pragma unroll
      for (int t = 0; t < 8; ++t){
        unsigned old = atomicCAS(&hk[h], 0xFFFFFFFFu, key);
        if (old == 0xFFFFFFFFu || old == key){ atomicMin(&hw[h], wb); ins = true; break; }
        h = (h + 1) & (LHSZ-1);
      }
      if (!ins){
        spill = true;
        rec = ((u64)wb << 32) | ((u64)sme[a] << 16) | sme[b];
      }
    }
    u64 m = __ballot(spill);
    if (m){
      int pos0 = __popcll(m & ((1ULL<<lane)-1));
      int leader = __ffsll((long long)m)-1;
      unsigned base = 0;
      if (lane == leader) base = atomicAdd(ctr, (unsigned)__popcll(m));
      base = (unsigned)__shfl((int)base, leader);
      if (spill) LA[base + pos0] = rec;
    }
  }
  __syncthreads();
  // flush hash: one record per distinct pair, weight = pair min
  for (int h = tid; h < LHSZ; h += LTPB){
    unsigned key = hk[h];
    bool ok = (key != 0xFFFFFFFFu);
    u64 rec = 0;
    if (ok){
      int a = (int)(key >> 11), b = (int)(key & 0x7FFu);
      rec = ((u64)hw[h] << 32) | ((u64)sme[a] << 16) | sme[b];
    }
    u64 m = __ballot(ok);
    if (m){
      int pos0 = __popcll(m & ((1ULL<<lane)-1));
      int leader = __ffsll((long long)m)-1;
      unsigned base = 0;
      if (lane == leader) base = atomicAdd(ctr, (unsigned)__popcll(m));
      base = (unsigned)__shfl((int)base, leader);
      if (ok) LA[base + pos0] = rec;
    }
  }
}

// fallback rounds (K>KMAX, safety net) — global arrays, fmt16, no dedupe
#define RUN_ROUNDS_GLOBAL(UF, ME, RNK)                                       \
  for (int k = tid; k < K; k += ETPB){                                       \
    unsigned g = kg[k];                                                      \
    UF[k] = (unsigned short)k;                                               \
    RNK[k] = ((u64)__float_as_uint(f[g]) << 32) | g;                         \
  }                                                                          \
  __syncthreads();                                                           \
  for (int rd = 0; rd < 70000 && n > 0; ++rd){                               \
    for (int k = tid; k < K; k += ETPB) ME[k] = 0xFFFFFFFFu;                 \
    if (tid == 0) s_n[0] = 0;                                                \
    __syncthreads();                                                         \
    int Mpad = (n + 63) & ~63;                                               \
    for (int idx = tid; idx < Mpad; idx += ETPB){                            \
      bool keep = false; unsigned wb = 0; int a = 0, b = 0;                  \
      if (idx < n){                                                          \
        u64 rec = src[idx];                                                  \
        wb = (unsigned)(rec >> 32);                                          \
        a = (int)((rec >> 16) & 0xFFFFu);                                    \
        b = (int)(rec & 0xFFFFu);                                            \
        a = ufind16(UF, a); b = ufind16(UF, b);                              \
        if (a != b){ atomicMin(&ME[a], wb); atomicMin(&ME[b], wb); keep = true; } \
      }                                                                      \
      u64 m = __ballot(keep);                                                \
      if (m){                                                                \
        int pos0 = __popcll(m & ((1ULL<<lane)-1));                           \
        int leader = __ffsll((long long)m)-1;                                \
        int base = 0;                                                        \
        if (lane == leader) base = atomicAdd(&s_n[0], __popcll(m));          \
        base = __shfl(base, leader);                                         \
        if (keep) dst[base+pos0] = ((u64)wb<<32)|((u64)(unsigned)a<<16)|(unsigned)b; \
      }                                                                      \
    }                                                                        \
    __syncthreads();                                                         \
    int nn = s_n[0];                                                         \
    for (int idx = tid; idx < nn; idx += ETPB){                              \
      u64 rec = dst[idx];                                                    \
      unsigned wb = (unsigned)(rec >> 32);                                   \
      int a = (int)((rec >> 16) & 0xFFFFu);                                  \
      int b = (int)(rec & 0xFFFFu);                                          \
      bool bd = RNK[b] < RNK[a];                                             \
      int die = bd ? a : b, kp = bd ? b : a;                                 \
      if (ME[die] == wb){                                                    \
        UF[die] = (unsigned short)kp;                                        \
        u64 rk = RNK[die];                                                   \
        life[(unsigned)(rk & 0xFFFFFFFFu)] =                                 \
            __uint_as_float(wb) - __uint_as_float((unsigned)(rk >> 32));     \
      }                                                                      \
    }                                                                        \
    __syncthreads();                                                         \
    u64* t = src; src = dst; dst = t; n = nn;                                \
  }

// ---------------- endgame: 1 block/image, LDS union-find + dedupe ----------------
__global__ __launch_bounds__(ETPB)
void ph0_endgame(const float* __restrict__ Fg, float* __restrict__ LIFEg,
                 unsigned* __restrict__ LBLg, unsigned* __restrict__ MAPg,
                 unsigned* __restrict__ KGg, u64* __restrict__ LAg,
                 u64* __restrict__ LBg, u64* __restrict__ GRg,
                 const unsigned* __restrict__ C, const unsigned* __restrict__ C2,
                 float* __restrict__ LOSS, unsigned* __restrict__ DONE,
                 float* __restrict__ out)
{
  const int img = blockIdx.x, tid = threadIdx.x;
  const int lane = tid & 63;
  const float* f = Fg + img*NPIX;
  float* life = LIFEg + img*NPIX;
  unsigned* lblg = LBLg + img*NPIX;
  unsigned* map  = MAPg + img*NPIX;
  const unsigned* kg = KGg + img*NPIX;
  u64* src = LAg + (size_t)img*NE;
  u64* dst = LBg + (size_t)img*NE;
  u64* rnk = GRg + (size_t)img*NPIX;   // ranks in global (L2) — read-mostly

  __shared__ u64 smem8[7168];          // 57344 B carved:
  unsigned short* s_uf = (unsigned short*)smem8;              // 16 KB (K<=8192)
  unsigned* s_me = (unsigned*)((char*)smem8 + 16384);         // 32 KB
  unsigned* s_hk = (unsigned*)((char*)smem8 + 49152);         // 4 KB
  unsigned* s_hw = (unsigned*)((char*)smem8 + 53248);         // 4 KB
  __shared__ int s_n[3];

  const int K = (int)C2[img];
  const int nInt = (int)C[img];

  // append the 2560 cut edges (translated to compact ids, fmt16)
  for (int s = tid; s < 2560; s += ETPB){
    int gu, gv;
    if (s < 768){ int ci = s >> 8, row = s & 255, col = 63 + (ci<<6); gu = (row<<8)+col; gv = gu+1; }
    else { int k = s - 768; int ri = k >> 8, colh = k & 255, gr = 31 + (ri<<5); gu = (gr<<8)+colh; gv = gu+256; }
    unsigned ia = map[lblg[gu]];
    unsigned ib = map[lblg[gv]];
    unsigned wb = __float_as_uint(fmaxf(f[gu], f[gv]));
    src[nInt + s] = ((u64)wb << 32) | ((u64)ia << 16) | ib;
  }
  if (tid < 3) s_n[tid] = 0;
  int n = nInt + 2560;
  __syncthreads();

  if (K <= KMAX){
    for (int k = tid; k < K; k += ETPB){
      unsigned g = kg[k];
      s_uf[k] = (unsigned short)k;
      rnk[k] = ((u64)__float_as_uint(f[g]) << 32) | g;   // (birth fbits, pixel): lower = deeper
    }
    __syncthreads();
    for (int rd = 0; rd < 70000; ++rd){
      bool useHash = (n > 1024);
      for (int k = tid; k < K; k += ETPB) s_me[k] = 0xFFFFFFFFu;
      if (useHash)
        for (int h = tid; h < HSZ; h += ETPB){ s_hk[h] = 0xFFFFFFFFu; s_hw[h] = 0xFFFFFFFFu; }
      if (tid == 0) s_n[(rd+1)%3] = 0;
      __syncthreads();                      // A
      int Mpad = (n + 63) & ~63;
      // pass A: relabel; hash-dedupe (big rounds) or direct mins; append live
      for (int idx = tid; idx < Mpad; idx += ETPB){
        bool app = false; unsigned wb = 0; int a = 0, b = 0;
        if (idx < n){
          u64 rec = src[idx];
          a = (int)((rec >> 16) & 0xFFFFu);
          b = (int)(rec & 0xFFFFu);
          a = ufind16(s_uf, a); b = ufind16(s_uf, b);
          if (a != b){
            wb = (unsigned)(rec >> 32);
            if (useHash){
              int lo = a < b ? a : b, hi = a < b ? b : a;
              unsigned key = ((unsigned)lo << 13) | (unsigned)hi;   // ids<8192 -> 26 bits
              unsigned h = ((key * 2654435761u) >> 22) & (HSZ-1);
              bool ins = false;
              #pragma unroll
              for (int t = 0; t < 8; ++t){
                unsigned old = atomicCAS(&s_hk[h], 0xFFFFFFFFu, key);
                if (old == 0xFFFFFFFFu || old == key){ atomicMin(&s_hw[h], wb); ins = true; break; }
                h = (h + 1) & (HSZ-1);
              }
              if (!ins){ atomicMin(&s_me[a], wb); atomicMin(&s_me[b], wb); app = true; }
            } else {
              atomicMin(&s_me[a], wb); atomicMin(&s_me[b], wb); app = true;
            }
          }
        }
        u64 m = __ballot(app);
        if (m){
          int pos0 = __popcll(m & ((1ULL<<lane)-1));
          int leader = __ffsll((long long)m)-1;
          int base = 0;
          if (lane == leader) base = atomicAdd(&s_n[rd%3], __popcll(m));
          base = __shfl(base, leader);
          if (app) dst[base+pos0] = ((u64)wb<<32)|((u64)(unsigned)a<<16)|(unsigned)b;
        }
      }
      __syncthreads();                      // B1
      if (useHash){
        // pass B: flush hash — one deduped record per pair
        for (int h = tid; h < HSZ; h += ETPB){
          unsigned key = s_hk[h];
          bool okk = (key != 0xFFFFFFFFu);
          unsigned wb = 0; int a = 0, b = 0;
          if (okk){
            a = (int)(key >> 13); b = (int)(key & 0x1FFFu);
            wb = s_hw[h];
            atomicMin(&s_me[a], wb); atomicMin(&s_me[b], wb);
          }
          u64 m = __ballot(okk);
          if (m){
            int pos0 = __popcll(m & ((1ULL<<lane)-1));
            int leader = __ffsll((long long)m)-1;
            int base = 0;
            if (lane == leader) base = atomicAdd(&s_n[rd%3], __popcll(m));
            base = __shfl(base, leader);
            if (okk) dst[base+pos0] = ((u64)wb<<32)|((u64)(unsigned)a<<16)|(unsigned)b;
          }
        }
        __syncthreads();                    // B2
      }
      int nn = s_n[rd%3];
      // hashless: nn == n  <=>  zero fires last round (impossible mid-stream;
      // safety) — real exit is nn == 0 (single component left)
      if (nn == 0 || (!useHash && rd > 0 && nn == n)) break;
      // pass C: fire via pass-A roots (frozen in records) — exact elder rule
      for (int idx = tid; idx < nn; idx += ETPB){
        u64 rec = dst[idx];
        unsigned wb = (unsigned)(rec >> 32);
        int a = (int)((rec >> 16) & 0xFFFFu);
        int b = (int)(rec & 0xFFFFu);
        u64 ra = rnk[a], rb = rnk[b];
        bool bd = rb < ra;
        int die = bd ? a : b, kp = bd ? b : a;
        if (s_me[die] == wb){
          s_uf[die] = (unsigned short)kp;
          u64 rk = bd ? ra : rb;
          life[(unsigned)(rk & 0xFFFFFFFFu)] =
              __uint_as_float(wb) - __uint_as_float((unsigned)(rk >> 32));
        }
      }
      __syncthreads();                      // C
      u64* t = src; src = dst; dst = t;
      n = nn;
    }
  } else {
    unsigned short* g_uf = (unsigned short*)lblg;   // dead after translation
    unsigned*       g_me = map;                     // dead after translation
    u64*            g_rnk = rnk;
    RUN_ROUNDS_GLOBAL(g_uf, g_me, g_rnk)
  }

  // ---- top-5 lifetimes -> per-image loss (scratch aliases smem8) ----
  float* cand = (float*)smem8;
  float* sval = (float*)smem8 + ETPB*5;
  int*   sidx = (int*)((float*)smem8 + ETPB*6);
  __syncthreads();

  float t5[5] = {-1.f,-1.f,-1.f,-1.f,-1.f};
  for (int i = tid; i < NPIX; i += ETPB){
    float v = life[i];
    if (v > t5[4]){
      int j = 4;
      while (j > 0 && t5[j-1] < v){ t5[j] = t5[j-1]; --j; }
      t5[j] = v;
    }
  }
  #pragma unroll
  for (int k = 0; k < 5; ++k) cand[tid*5+k] = t5[k];
  __syncthreads();

  float lsum = 0.0f;
  for (int k = 0; k < 5; ++k){
    float bv = -1.0f; int bi = 0;
    #pragma unroll
    for (int j = 0; j < 5; ++j){
      float v = cand[tid*5+j];
      if (v > bv){ bv = v; bi = tid*5+j; }
    }
    sval[tid] = bv; sidx[tid] = bi;
    __syncthreads();
    for (int off = ETPB>>1; off > 0; off >>= 1){
      if (tid < off && sval[tid+off] > sval[tid]){
        sval[tid] = sval[tid+off]; sidx[tid] = sidx[tid+off];
      }
      __syncthreads();
    }
    float win = sval[0];
    if (tid == 0) cand[sidx[0]] = -2.0f;
    float d = win - 0.5f;                  // TARGET_LIFETIME
    lsum += d*d;
    __syncthreads();
  }

  if (tid == 0){
    atomicExch(&LOSS[img], lsum * 0.2f);   // n_use = 5 always (65535 valid pairs)
    __threadfence();
    unsigned prev = atomicAdd(DONE, 1u);
    if (prev == NIMG - 1){
      float s = 0.0f;
      #pragma unroll
      for (int i = 0; i < NIMG; ++i) s += atomicAdd(&LOSS[i], 0.0f);
      out[0] = s * 25.0f;                  // mean over 4 * LOSS_SCALE(100)
    }
  }
}

extern "C" void kernel_launch(void* const* d_in, const int* in_sizes, int n_in,
                              void* d_out, int out_size, void* d_ws, size_t ws_size,
                              hipStream_t stream)
{
  const float* prob = (const float*)d_in[0];
  const float* roi  = (const float*)d_in[1];
  char* ws = (char*)d_ws;
  const size_t SZL = (size_t)4*NE*8;              // 4,177,920 B per list
  float*    F    = (float*)(ws);
  float*    LIFE = (float*)(ws + (1u<<20));
  unsigned* LBL  = (unsigned*)(ws + (2u<<20));
  unsigned* MAP  = (unsigned*)(ws + (3u<<20));
  unsigned* KG   = (unsigned*)(ws + (4u<<20));
  u64*      LA   = (u64*)(ws + (5u<<20));
  u64*      LB   = (u64*)(ws + (5u<<20) + SZL);
  u64*      GR   = (u64*)(ws + (5u<<20) + 2*SZL);
  unsigned* C    = (unsigned*)(ws + (5u<<20) + 2*SZL + (2u<<20));
  unsigned* C2   = C + 4;
  unsigned* DONE = C + 8;
  float*    LOSS = (float*)((char*)C + 64);
  float*    out  = (float*)d_out;

  hipMemsetAsync(C, 0, 64, stream);   // C, C2, DONE (capture-safe memset node)
  ph0_local<<<NBLK_L, LTPB, 0, stream>>>(prob, roi, F, LIFE, LBL, LA, C, C2, MAP, KG);
  ph0_endgame<<<NIMG, ETPB, 0, stream>>>(F, LIFE, LBL, MAP, KG, LA, LB, GR, C, C2, LOSS, DONE, out);
}

// Round 9
// 313.678 us; speedup vs baseline: 1.8087x; 1.8087x over previous
//
#include <hip/hip_runtime.h>
#include <stdint.h>

#define NPIX 65536      // 256*256
#define NRE  65280      // right edges: 256 rows * 255
#define NE   130560     // total edges
#define NIMG 4
#define LTPB 1024                // local kernel threads (R8 showed fewer threads regress)
#define ETPB 1024                // endgame threads
#define NBLK_L (NIMG*32)         // 128 local blocks (32 tiles/image, 32x64 each)
#define TPIX 2048
#define EPAD 4096                // local edge-id space (H:[0,2048) V:[2048,4096))
#define KMAX 4096                // max components/image for LDS endgame (R5: K<=4096 held)
#define HSZ  1024                // endgame LDS dedupe hash slots (per buffer)
#define LHSZ 2048                // local emit dedupe hash slots
typedef unsigned long long u64;

// union-find, path compression; roots stable within a phase -> races benign
__device__ __forceinline__ int ufind(unsigned* lbl, int x){
  int r = x, c = (int)lbl[r];
  while (c != r){ r = c; c = (int)lbl[r]; }
  while ((int)lbl[x] != r){ int n = (int)lbl[x]; lbl[x] = (unsigned)r; x = n; }
  return r;
}
__device__ __forceinline__ int ufind16(unsigned short* uf, int x){
  int r = x, c = (int)uf[r];
  while (c != r){ r = c; c = (int)uf[r]; }
  while ((int)uf[x] != r){ int n = (int)uf[x]; uf[x] = (unsigned short)r; x = n; }
  return r;
}

// merge two descending-sorted 5-lists (b into a)
__device__ __forceinline__ void merge5(float* a, const float* b){
  float out[5]; int ia = 0, ib = 0;
  #pragma unroll
  for (int k = 0; k < 5; ++k){
    float av = (ia < 5) ? a[ia] : -2.0f;
    float bv = (ib < 5) ? b[ib] : -2.0f;
    if (av >= bv){ out[k] = av; ++ia; } else { out[k] = bv; ++ib; }
  }
  #pragma unroll
  for (int k = 0; k < 5; ++k) a[k] = out[k];
}

// ---------------- local (tile) kernel: LDS union-find contraction ----------------
__global__ __launch_bounds__(LTPB)
void ph0_local(const float* __restrict__ prob, const float* __restrict__ roi,
               float* __restrict__ Fg, float* __restrict__ LIFEg,
               unsigned* __restrict__ LBLg, u64* __restrict__ LAg,
               unsigned* __restrict__ C, unsigned* __restrict__ C2,
               unsigned* __restrict__ MAPg, unsigned* __restrict__ KGg)
{
  const int blk = blockIdx.x;
  const int img = blk >> 5;
  const int tile = blk & 31;
  const int tr = tile >> 2, tc = tile & 3;     // 8 rows x 4 cols of tiles
  const int gr0 = tr*32, gc0 = tc*64;
  const int tid = threadIdx.x;
  const int lane = tid & 63;

  const float* pm = prob + img*NPIX;
  const float* rm = roi  + img*NPIX;
  float* F = Fg + img*NPIX;
  float* LIFE = LIFEg + img*NPIX;
  unsigned* LBL = LBLg + img*NPIX;
  unsigned* MAP = MAPg + img*NPIX;
  unsigned* KG  = KGg  + img*NPIX;
  u64* LA = LAg + (size_t)img*NE;

  __shared__ float          sf[TPIX];      // 8 KB
  __shared__ unsigned       slbl[TPIX];    // 8 KB (later: dedupe hash weights)
  __shared__ unsigned       sme[TPIX];     // 8 KB (min weight per root; later pos-map)
  __shared__ unsigned short el[2][EPAD];   // 16 KB ping-pong edge lists (free half: hash keys)
  __shared__ unsigned       aux[EPAD];     // 16 KB round-start roots (a|b<<16)
  __shared__ unsigned       bkw[192];      // cut-edge blocker weights
  __shared__ unsigned short bkp[192];      // blocker pixel (local id)
  __shared__ int s_n[3];                   // rotating round counters

  for (int p = tid; p < TPIX; p += LTPB){
    int gp = ((gr0 + (p>>6))<<8) + gc0 + (p&63);
    float fv = 1.0f - pm[gp]*rm[gp];
    sf[p] = fv; slbl[p] = (unsigned)p;
    F[gp] = fv; LIFE[gp] = 0.0f;
  }
  if (tid < 3) s_n[tid] = 0;
  // blocker table: for each tile-boundary pixel, min cut-edge weight
  for (int s = tid; s < 192; s += LTPB){
    unsigned wv = 0xFFFFFFFFu; int p = 0; int gq = -1;
    if (s < 32){ if (tc > 0){ p = s*64;        gq = ((gr0+s)<<8)    + gc0 - 1;  } }
    else if (s < 64){ int k=s-32;  if (tc < 3){ p = k*64+63;  gq = ((gr0+k)<<8)  + gc0 + 64; } }
    else if (s < 128){ int k=s-64; if (tr > 0){ p = k;        gq = ((gr0-1)<<8)  + gc0 + k;  } }
    else { int k=s-128;            if (tr < 7){ p = 31*64+k;  gq = ((gr0+32)<<8) + gc0 + k;  } }
    if (gq >= 0){
      int gp = ((gr0 + (p>>6))<<8) + gc0 + (p&63);
      float fp = 1.0f - pm[gp]*rm[gp];
      float fq = 1.0f - pm[gq]*rm[gq];
      wv = __float_as_uint(fmaxf(fp, fq));
    }
    bkw[s] = wv; bkp[s] = (unsigned short)p;
  }
  __syncthreads();

  // ---- local rounds: 3 barriers/round; exit when list stops shrinking ----
  int M = EPAD, cur = 0;
  for (int rd = 0; rd < 100000; ++rd){
    int nxt = cur ^ 1;
    for (int i = tid; i < TPIX; i += LTPB) sme[i] = 0xFFFFFFFFu;
    if (tid == 0) s_n[(rd+1)%3] = 0;
    __syncthreads();                       // A: prev fires + resets visible
    if (tid < 192){
      unsigned wv = bkw[tid];
      if (wv != 0xFFFFFFFFu) atomicMin(&sme[ufind(slbl, (int)bkp[tid])], wv);
    }
    int Mpad = (M + 63) & ~63;
    // phase 1: relabel, compact survivors, per-root min weight
    for (int idx = tid; idx < Mpad; idx += LTPB){
      bool keep = false; int e=0,u=0,v=0,a=0,b=0;
      if (idx < M){
        e = (rd == 0) ? idx : (int)el[cur][idx];
        bool valid;
        if (e < 2048){ u=e; v=e+1; valid = ((e&63)!=63); }
        else { u=e-2048; v=u+64; valid = ((u>>6)!=31); }
        if (valid){
          a = ufind(slbl,u); b = ufind(slbl,v);
          if (a != b){
            unsigned wb = __float_as_uint(fmaxf(sf[u],sf[v]));
            atomicMin(&sme[a],wb); atomicMin(&sme[b],wb);
            keep = true;
          }
        }
      }
      u64 m = __ballot(keep);
      if (m){
        int pos0 = __popcll(m & ((1ULL<<lane)-1));
        int leader = __ffsll((long long)m)-1;
        int base = 0;
        if (lane == leader) base = atomicAdd(&s_n[rd%3], __popcll(m));
        base = __shfl(base, leader);
        if (keep){
          el[nxt][base+pos0] = (unsigned short)e;
          aux[base+pos0] = (unsigned)a | ((unsigned)b<<16);
        }
      }
    }
    __syncthreads();                       // B: mins + list complete
    int n = s_n[rd%3];
    cur = nxt;
    // n == M  <=>  previous round had zero fires  =>  stable (blocked) state
    if (n == M || n == 0){ M = n; break; }
    M = n;
    // phase 2: fire via round-start roots (frozen in aux) — exact elder rule
    for (int idx = tid; idx < M; idx += LTPB){
      int e = (int)el[cur][idx];
      unsigned ab = aux[idx];
      int a = (int)(ab & 0xFFFFu), b = (int)(ab >> 16);
      int u, v;
      if (e < 2048){ u = e; v = e + 1; } else { u = e - 2048; v = u + 64; }
      float w = fmaxf(sf[u], sf[v]);
      unsigned wb = __float_as_uint(w);
      float fa = sf[a], fb = sf[b];
      bool bd = (fb < fa) || ((fb == fa) && (b < a));   // local order == global order in-tile
      int die = bd ? a : b, keep = bd ? b : a;
      if (sme[die] == wb){
        slbl[die] = (unsigned)keep;
        int gd = ((gr0 + (die>>6))<<8) + gc0 + (die&63);
        LIFE[gd] = w - (bd ? fa : fb);
      }
    }
    __syncthreads();                       // C: fires + sme reads done before next reset
  }

  // ---- final relabel, compact roots to dense per-image ids ----
  for (int p = tid; p < TPIX; p += LTPB){
    int r = ufind(slbl, p);
    int gp = ((gr0 + (p>>6))<<8) + gc0 + (p&63);
    LBL[gp] = (unsigned)(((gr0 + (r>>6))<<8) + gc0 + (r&63));
  }
  __syncthreads();                         // slbl fully compressed; sme reusable
  for (int p = tid; p < TPIX; p += LTPB){
    if ((int)slbl[p] == p){
      unsigned pos = atomicAdd(&C2[img], 1u);
      sme[p] = pos;                        // in-tile pos map
      unsigned gp = (unsigned)(((gr0 + (p>>6))<<8) + gc0 + (p&63));
      MAP[gp] = pos;
      KG[pos] = gp;
    }
  }
  __syncthreads();

  // ---- emit surviving internal edges, deduped per root-pair ----
  unsigned* hk = (unsigned*)&el[cur ^ 1][0];   // 2048 u32 slots (free ping-pong half)
  unsigned* hw = slbl;                          // 2048 u32 slots (dead)
  for (int i = tid; i < LHSZ; i += LTPB){ hk[i] = 0xFFFFFFFFu; hw[i] = 0xFFFFFFFFu; }
  __syncthreads();

  unsigned* ctr = &C[img];
  int Mpad2 = (M + 63) & ~63;
  for (int idx = tid; idx < Mpad2; idx += LTPB){
    bool spill = false;
    u64 rec = 0;
    if (idx < M){
      int e = (int)el[cur][idx];
      unsigned ab = aux[idx];              // round-start roots == final roots (0 fires)
      int a = (int)(ab & 0xFFFFu), b = (int)(ab >> 16);
      int u, v;
      if (e < 2048){ u = e; v = e + 1; } else { u = e - 2048; v = u + 64; }
      unsigned wb = __float_as_uint(fmaxf(sf[u], sf[v]));
      int lo = a < b ? a : b, hi = a < b ? b : a;
      unsigned key = ((unsigned)lo << 11) | (unsigned)hi;   // a,b < 2048 -> 22 bits
      unsigned h = ((key * 2654435761u) >> 21) & (LHSZ-1);
      bool ins = false;
      #pragma unroll
      for (int t = 0; t < 8; ++t){
        unsigned old = atomicCAS(&hk[h], 0xFFFFFFFFu, key);
        if (old == 0xFFFFFFFFu || old == key){ atomicMin(&hw[h], wb); ins = true; break; }
        h = (h + 1) & (LHSZ-1);
      }
      if (!ins){
        spill = true;
        rec = ((u64)wb << 32) | ((u64)sme[a] << 16) | sme[b];
      }
    }
    u64 m = __ballot(spill);
    if (m){
      int pos0 = __popcll(m & ((1ULL<<lane)-1));
      int leader = __ffsll((long long)m)-1;
      unsigned base = 0;
      if (lane == leader) base = atomicAdd(ctr, (unsigned)__popcll(m));
      base = (unsigned)__shfl((int)base, leader);
      if (spill) LA[base + pos0] = rec;
    }
  }
  __syncthreads();
  // flush hash: one record per distinct pair, weight = pair min
  for (int h = tid; h < LHSZ; h += LTPB){
    unsigned key = hk[h];
    bool ok = (key != 0xFFFFFFFFu);
    u64 rec = 0;
    if (ok){
      int a = (int)(key >> 11), b = (int)(key & 0x7FFu);
      rec = ((u64)hw[h] << 32) | ((u64)sme[a] << 16) | sme[b];
    }
    u64 m = __ballot(ok);
    if (m){
      int pos0 = __popcll(m & ((1ULL<<lane)-1));
      int leader = __ffsll((long long)m)-1;
      unsigned base = 0;
      if (lane == leader) base = atomicAdd(ctr, (unsigned)__popcll(m));
      base = (unsigned)__shfl((int)base, leader);
      if (ok) LA[base + pos0] = rec;
    }
  }
}

// fallback rounds (K>KMAX, safety net) — global arrays, fmt16, no dedupe
#define RUN_ROUNDS_GLOBAL(UF, ME, RNK)                                       \
  for (int k = tid; k < K; k += ETPB){                                       \
    unsigned g = kg[k];                                                      \
    UF[k] = (unsigned short)k;                                               \
    RNK[k] = ((u64)__float_as_uint(f[g]) << 32) | g;                         \
  }                                                                          \
  __syncthreads();                                                           \
  for (int rd = 0; rd < 70000 && n > 0; ++rd){                               \
    for (int k = tid; k < K; k += ETPB) ME[k] = 0xFFFFFFFFu;                 \
    if (tid == 0) s_n[0] = 0;                                                \
    __syncthreads();                                                         \
    int Mpad = (n + 63) & ~63;                                               \
    for (int idx = tid; idx < Mpad; idx += ETPB){                            \
      bool keep = false; unsigned wb = 0; int a = 0, b = 0;                  \
      if (idx < n){                                                          \
        u64 rec = src[idx];                                                  \
        wb = (unsigned)(rec >> 32);                                          \
        a = (int)((rec >> 16) & 0xFFFFu);                                    \
        b = (int)(rec & 0xFFFFu);                                            \
        a = ufind16(UF, a); b = ufind16(UF, b);                              \
        if (a != b){ atomicMin(&ME[a], wb); atomicMin(&ME[b], wb); keep = true; } \
      }                                                                      \
      u64 m = __ballot(keep);                                                \
      if (m){                                                                \
        int pos0 = __popcll(m & ((1ULL<<lane)-1));                           \
        int leader = __ffsll((long long)m)-1;                                \
        int base = 0;                                                        \
        if (lane == leader) base = atomicAdd(&s_n[0], __popcll(m));          \
        base = __shfl(base, leader);                                         \
        if (keep) dst[base+pos0] = ((u64)wb<<32)|((u64)(unsigned)a<<16)|(unsigned)b; \
      }                                                                      \
    }                                                                        \
    __syncthreads();                                                         \
    int nn = s_n[0];                                                         \
    for (int idx = tid; idx < nn; idx += ETPB){                              \
      u64 rec = dst[idx];                                                    \
      unsigned wb = (unsigned)(rec >> 32);                                   \
      int a = (int)((rec >> 16) & 0xFFFFu);                                  \
      int b = (int)(rec & 0xFFFFu);                                          \
      bool bd = RNK[b] < RNK[a];                                             \
      int die = bd ? a : b, kp = bd ? b : a;                                 \
      if (ME[die] == wb){                                                    \
        UF[die] = (unsigned short)kp;                                        \
        u64 rk = RNK[die];                                                   \
        life[(unsigned)(rk & 0xFFFFFFFFu)] =                                 \
            __uint_as_float(wb) - __uint_as_float((unsigned)(rk >> 32));     \
      }                                                                      \
    }                                                                        \
    __syncthreads();                                                         \
    u64* t = src; src = dst; dst = t; n = nn;                                \
  }

// ---------------- endgame: 1 block/image, LDS UF + dedupe, 2-barrier rounds ----------------
__global__ __launch_bounds__(ETPB)
void ph0_endgame(const float* __restrict__ Fg, float* __restrict__ LIFEg,
                 unsigned* __restrict__ LBLg, unsigned* __restrict__ MAPg,
                 unsigned* __restrict__ KGg, u64* __restrict__ LAg,
                 u64* __restrict__ LBg, u64* __restrict__ GRg,
                 const unsigned* __restrict__ C, const unsigned* __restrict__ C2,
                 float* __restrict__ LOSS, unsigned* __restrict__ DONE,
                 float* __restrict__ out)
{
  const int img = blockIdx.x, tid = threadIdx.x;
  const int lane = tid & 63;
  const float* f = Fg + img*NPIX;
  float* life = LIFEg + img*NPIX;
  unsigned* lblg = LBLg + img*NPIX;
  unsigned* map  = MAPg + img*NPIX;
  const unsigned* kg = KGg + img*NPIX;
  u64* src = LAg + (size_t)img*NE;
  u64* dst = LBg + (size_t)img*NE;
  u64* rnk = GRg + (size_t)img*NPIX;   // ranks in global (L2) — read-mostly

  __shared__ u64 smem8[7208];          // 57664 B carved:
  unsigned short* s_uf = (unsigned short*)smem8;              //  8 KB (K<=4096)
  unsigned* s_meB = (unsigned*)((char*)smem8 + 8192);         // 32 KB (2 buffers x 4096)
  unsigned* s_hkB = (unsigned*)((char*)smem8 + 40960);        //  8 KB (2 x 1024)
  unsigned* s_hwB = (unsigned*)((char*)smem8 + 49152);        //  8 KB (2 x 1024)
  float*    s_w5  = (float*)((char*)smem8 + 57344);           // 320 B (16 waves x 5)
  __shared__ int s_n[3];

  const int K = (int)C2[img];
  const int nInt = (int)C[img];

  // append the 2560 cut edges (translated to compact ids, fmt16)
  for (int s = tid; s < 2560; s += ETPB){
    int gu, gv;
    if (s < 768){ int ci = s >> 8, row = s & 255, col = 63 + (ci<<6); gu = (row<<8)+col; gv = gu+1; }
    else { int k = s - 768; int ri = k >> 8, colh = k & 255, gr = 31 + (ri<<5); gu = (gr<<8)+colh; gv = gu+256; }
    unsigned ia = map[lblg[gu]];
    unsigned ib = map[lblg[gv]];
    unsigned wb = __float_as_uint(fmaxf(f[gu], f[gv]));
    src[nInt + s] = ((u64)wb << 32) | ((u64)ia << 16) | ib;
  }
  if (tid < 3) s_n[tid] = 0;
  int n = nInt + 2560;

  if (K <= KMAX){
    // init phase: uf, rank, me[0], hash[0] (round 0 always hashes: n >= 2560)
    for (int k = tid; k < K; k += ETPB){
      unsigned g = kg[k];
      s_uf[k] = (unsigned short)k;
      rnk[k] = ((u64)__float_as_uint(f[g]) << 32) | g;   // (birth fbits, pixel): lower = deeper
      s_meB[k] = 0xFFFFFFFFu;
    }
    for (int h = tid; h < HSZ; h += ETPB){ s_hkB[h] = 0xFFFFFFFFu; s_hwB[h] = 0xFFFFFFFFu; }
    __syncthreads();

    for (int rd = 0; rd < 70000; ++rd){
      const int bi = rd & 1;
      unsigned* me = s_meB + bi*KMAX;
      unsigned* hk = s_hkB + bi*HSZ;
      unsigned* hw = s_hwB + bi*HSZ;
      const bool useHash = (n > 1024);
      int Mpad = (n + 63) & ~63;
      // pass A: relabel; hash-dedupe (big rounds) or direct mins; append live
      for (int idx = tid; idx < Mpad; idx += ETPB){
        bool app = false; unsigned wb = 0; int a = 0, b = 0;
        if (idx < n){
          u64 rec = src[idx];
          a = (int)((rec >> 16) & 0xFFFFu);
          b = (int)(rec & 0xFFFFu);
          a = ufind16(s_uf, a); b = ufind16(s_uf, b);
          if (a != b){
            wb = (unsigned)(rec >> 32);
            if (useHash){
              int lo = a < b ? a : b, hi = a < b ? b : a;
              unsigned key = ((unsigned)lo << 12) | (unsigned)hi;   // ids<4096 -> 24 bits
              unsigned h = ((key * 2654435761u) >> 20) & (HSZ-1);
              bool ins = false;
              #pragma unroll
              for (int t = 0; t < 8; ++t){
                unsigned old = atomicCAS(&hk[h], 0xFFFFFFFFu, key);
                if (old == 0xFFFFFFFFu || old == key){ atomicMin(&hw[h], wb); ins = true; break; }
                h = (h + 1) & (HSZ-1);
              }
              if (!ins){ atomicMin(&me[a], wb); atomicMin(&me[b], wb); app = true; }
            } else {
              atomicMin(&me[a], wb); atomicMin(&me[b], wb); app = true;
            }
          }
        }
        u64 m = __ballot(app);
        if (m){
          int pos0 = __popcll(m & ((1ULL<<lane)-1));
          int leader = __ffsll((long long)m)-1;
          int base = 0;
          if (lane == leader) base = atomicAdd(&s_n[rd%3], __popcll(m));
          base = __shfl(base, leader);
          if (app) dst[base+pos0] = ((u64)wb<<32)|((u64)(unsigned)a<<16)|(unsigned)b;
        }
      }
      __syncthreads();                      // B1
      if (useHash){
        // pass B: flush hash — one deduped record per pair
        for (int h = tid; h < HSZ; h += ETPB){
          unsigned key = hk[h];
          bool okk = (key != 0xFFFFFFFFu);
          unsigned wb = 0; int a = 0, b = 0;
          if (okk){
            a = (int)(key >> 12); b = (int)(key & 0xFFFu);
            wb = hw[h];
            atomicMin(&me[a], wb); atomicMin(&me[b], wb);
          }
          u64 m = __ballot(okk);
          if (m){
            int pos0 = __popcll(m & ((1ULL<<lane)-1));
            int leader = __ffsll((long long)m)-1;
            int base = 0;
            if (lane == leader) base = atomicAdd(&s_n[rd%3], __popcll(m));
            base = __shfl(base, leader);
            if (okk) dst[base+pos0] = ((u64)wb<<32)|((u64)(unsigned)a<<16)|(unsigned)b;
          }
        }
        __syncthreads();                    // B2 (only on hashed rounds)
      }
      int nn = s_n[rd%3];
      if (nn == 0) break;                   // endgame always progresses; exits via n==0
      // pass C: fire via pass-A roots (frozen in records) — exact elder rule.
      // Also: resets for round rd+1 (targets last touched in round rd-1 —
      // separated by C(rd-1) and B1(rd), so no extra barrier needed).
      for (int idx = tid; idx < nn; idx += ETPB){
        u64 rec = dst[idx];
        unsigned wb = (unsigned)(rec >> 32);
        int a = (int)((rec >> 16) & 0xFFFFu);
        int b = (int)(rec & 0xFFFFu);
        u64 ra = rnk[a], rb = rnk[b];
        bool bd = rb < ra;
        int die = bd ? a : b, kp = bd ? b : a;
        if (me[die] == wb){
          s_uf[die] = (unsigned short)kp;
          u64 rk = bd ? ra : rb;
          life[(unsigned)(rk & 0xFFFFFFFFu)] =
              __uint_as_float(wb) - __uint_as_float((unsigned)(rk >> 32));
        }
      }
      {
        unsigned* meN = s_meB + (bi^1)*KMAX;
        for (int k = tid; k < K; k += ETPB) meN[k] = 0xFFFFFFFFu;
        if (nn > 1024){
          unsigned* hkN = s_hkB + (bi^1)*HSZ;
          unsigned* hwN = s_hwB + (bi^1)*HSZ;
          for (int h = tid; h < HSZ; h += ETPB){ hkN[h] = 0xFFFFFFFFu; hwN[h] = 0xFFFFFFFFu; }
        }
        if (tid == 0) s_n[(rd+1)%3] = 0;
      }
      __syncthreads();                      // C
      u64* t = src; src = dst; dst = t;
      n = nn;
    }
  } else {
    __syncthreads();
    unsigned short* g_uf = (unsigned short*)lblg;   // dead after translation
    unsigned*       g_me = map;                     // dead after translation
    u64*            g_rnk = rnk;
    RUN_ROUNDS_GLOBAL(g_uf, g_me, g_rnk)
  }

  // ---- top-5 lifetimes via shuffle butterfly -> per-image loss ----
  float t5[5] = {-1.f,-1.f,-1.f,-1.f,-1.f};
  for (int i = tid; i < NPIX; i += ETPB){
    float v = life[i];
    if (v > t5[4]){
      int j = 4;
      while (j > 0 && t5[j-1] < v){ t5[j] = t5[j-1]; --j; }
      t5[j] = v;
    }
  }
  #pragma unroll
  for (int off = 1; off < 64; off <<= 1){
    float o[5];
    #pragma unroll
    for (int k = 0; k < 5; ++k) o[k] = __shfl_xor(t5[k], off);
    merge5(t5, o);
  }
  if (lane == 0){
    int wv = tid >> 6;
    #pragma unroll
    for (int k = 0; k < 5; ++k) s_w5[wv*5+k] = t5[k];
  }
  __syncthreads();
  if (tid < 64){
    float u5[5];
    #pragma unroll
    for (int k = 0; k < 5; ++k) u5[k] = (tid < ETPB/64) ? s_w5[tid*5+k] : -2.0f;
    #pragma unroll
    for (int off = 1; off < 16; off <<= 1){
      float o[5];
      #pragma unroll
      for (int k = 0; k < 5; ++k) o[k] = __shfl_xor(u5[k], off);
      merge5(u5, o);
    }
    if (tid == 0){
      float lsum = 0.0f;
      #pragma unroll
      for (int k = 0; k < 5; ++k){ float d = u5[k] - 0.5f; lsum += d*d; }  // TARGET_LIFETIME
      atomicExch(&LOSS[img], lsum * 0.2f);   // n_use = 5 always (65535 valid pairs)
      __threadfence();
      unsigned prev = atomicAdd(DONE, 1u);
      if (prev == NIMG - 1){
        float s = 0.0f;
        #pragma unroll
        for (int i = 0; i < NIMG; ++i) s += atomicAdd(&LOSS[i], 0.0f);
        out[0] = s * 25.0f;                  // mean over 4 * LOSS_SCALE(100)
      }
    }
  }
}

extern "C" void kernel_launch(void* const* d_in, const int* in_sizes, int n_in,
                              void* d_out, int out_size, void* d_ws, size_t ws_size,
                              hipStream_t stream)
{
  const float* prob = (const float*)d_in[0];
  const float* roi  = (const float*)d_in[1];
  char* ws = (char*)d_ws;
  const size_t SZL = (size_t)4*NE*8;              // 4,177,920 B per list
  float*    F    = (float*)(ws);
  float*    LIFE = (float*)(ws + (1u<<20));
  unsigned* LBL  = (unsigned*)(ws + (2u<<20));
  unsigned* MAP  = (unsigned*)(ws + (3u<<20));
  unsigned* KG   = (unsigned*)(ws + (4u<<20));
  u64*      LA   = (u64*)(ws + (5u<<20));
  u64*      LB   = (u64*)(ws + (5u<<20) + SZL);
  u64*      GR   = (u64*)(ws + (5u<<20) + 2*SZL);
  unsigned* C    = (unsigned*)(ws + (5u<<20) + 2*SZL + (2u<<20));
  unsigned* C2   = C + 4;
  unsigned* DONE = C + 8;
  float*    LOSS = (float*)((char*)C + 64);
  float*    out  = (float*)d_out;

  hipMemsetAsync(C, 0, 64, stream);   // C, C2, DONE (capture-safe memset node)
  ph0_local<<<NBLK_L, LTPB, 0, stream>>>(prob, roi, F, LIFE, LBL, LA, C, C2, MAP, KG);
  ph0_endgame<<<NIMG, ETPB, 0, stream>>>(F, LIFE, LBL, MAP, KG, LA, LB, GR, C, C2, LOSS, DONE, out);
}